// Round 6
// baseline (13657.423 us; speedup 1.0000x reference)
//
#include <hip/hip_runtime.h>
#include <math.h>

#define BATCH 16
#define SEQ 512
#define DIM 2048
#define HID 1024
#define NPAIRS 128
#define TLEN 384
#define NUN 256
#define BK 32

// ---------------------------------------------------------------------------
// GEMM 1: h = gelu(x @ imp_w1 + b1). fp64 accumulate (ascending k — bit-exact
// vs round-4/5), f64 tiles in LDS. 64x64 tile, BK=32.  (selection path!)
// ---------------------------------------------------------------------------
__global__ __launch_bounds__(256)
void cc_gemm_h(const float* __restrict__ A, const float* __restrict__ Bw,
               const float* __restrict__ bias, float* __restrict__ C) {
  const int N = HID, K = DIM;
  __shared__ double As[BK][66];
  __shared__ double Bs[BK][66];
  int tid = threadIdx.x;
  int tx = tid % 16, ty = tid / 16;
  int m0 = blockIdx.y * 64, n0 = blockIdx.x * 64;
  double acc[4][4] = {};
  for (int k0 = 0; k0 < K; k0 += BK) {
#pragma unroll
    for (int u = 0; u < 8; ++u) {
      int l = tid + u * 256;
      int r = l >> 5, k = l & 31;
      As[k][r] = (double)A[(size_t)(m0 + r) * K + k0 + k];
      int kb = l >> 6, n = l & 63;
      Bs[kb][n] = (double)Bw[(size_t)(k0 + kb) * N + n0 + n];
    }
    __syncthreads();
#pragma unroll
    for (int k = 0; k < BK; ++k) {
      double a0 = As[k][ty * 4 + 0], a1 = As[k][ty * 4 + 1];
      double a2 = As[k][ty * 4 + 2], a3 = As[k][ty * 4 + 3];
      double b0 = Bs[k][tx * 4 + 0], b1 = Bs[k][tx * 4 + 1];
      double b2 = Bs[k][tx * 4 + 2], b3 = Bs[k][tx * 4 + 3];
      acc[0][0] = fma(a0, b0, acc[0][0]); acc[0][1] = fma(a0, b1, acc[0][1]);
      acc[0][2] = fma(a0, b2, acc[0][2]); acc[0][3] = fma(a0, b3, acc[0][3]);
      acc[1][0] = fma(a1, b0, acc[1][0]); acc[1][1] = fma(a1, b1, acc[1][1]);
      acc[1][2] = fma(a1, b2, acc[1][2]); acc[1][3] = fma(a1, b3, acc[1][3]);
      acc[2][0] = fma(a2, b0, acc[2][0]); acc[2][1] = fma(a2, b1, acc[2][1]);
      acc[2][2] = fma(a2, b2, acc[2][2]); acc[2][3] = fma(a2, b3, acc[2][3]);
      acc[3][0] = fma(a3, b0, acc[3][0]); acc[3][1] = fma(a3, b1, acc[3][1]);
      acc[3][2] = fma(a3, b2, acc[3][2]); acc[3][3] = fma(a3, b3, acc[3][3]);
    }
    __syncthreads();
  }
#pragma unroll
  for (int i = 0; i < 4; ++i)
#pragma unroll
    for (int j = 0; j < 4; ++j) {
      int m = m0 + ty * 4 + i, n = n0 + tx * 4 + j;
      float pre = (float)(acc[i][j] + (double)bias[n]);     // f32 store point
      double v = (double)pre;
      double g = 0.5 * v * (1.0 + erf(v * 0.70710678118654752440));
      C[(size_t)m * N + n] = (float)g;                      // f32 store point
    }
}

// ---------------------------------------------------------------------------
// imp = sigmoid(h @ imp_w2 + b2); logit rounded to f32, imp stored f32
// ---------------------------------------------------------------------------
__global__ __launch_bounds__(256)
void cc_imp2(const float* __restrict__ h, const float* __restrict__ w2,
             const float* __restrict__ b2, float* __restrict__ imp) {
  int row = blockIdx.x, tid = threadIdx.x;
  __shared__ double red[256];
  double s = 0.0;
  const float* hr = h + (size_t)row * HID;
  for (int k = tid; k < HID; k += 256) s = fma((double)hr[k], (double)w2[k], s);
  red[tid] = s;
  __syncthreads();
  for (int off = 128; off > 0; off >>= 1) {
    if (tid < off) red[tid] += red[tid + off];
    __syncthreads();
  }
  if (tid == 0) {
    float logit = (float)(red[0] + (double)b2[0]);          // f32 store point
    double sg = 1.0 / (1.0 + exp(-(double)logit));
    imp[row] = (float)sg;                                   // f32 store point
  }
}

// ---------------------------------------------------------------------------
// per-batch min-max normalize in f32, then w = max(norm, 0.1f)
// ---------------------------------------------------------------------------
__global__ __launch_bounds__(512)
void cc_minmax(const float* __restrict__ imp, float* __restrict__ w) {
  int b = blockIdx.x, tid = threadIdx.x;
  __shared__ float mn[512], mx[512];
  float v = imp[b * SEQ + tid];
  mn[tid] = v; mx[tid] = v;
  __syncthreads();
  for (int off = 256; off > 0; off >>= 1) {
    if (tid < off) {
      mn[tid] = fminf(mn[tid], mn[tid + off]);
      mx[tid] = fmaxf(mx[tid], mx[tid + off]);
    }
    __syncthreads();
  }
  float lo = mn[0], hi = mx[0];
  float nv = (hi > lo) ? (v - lo) / (hi - lo) : v;
  w[b * SEQ + tid] = fmaxf(nv, 0.1f);
}

// ---------------------------------------------------------------------------
// row L2 norms of x: exact f64 sumsq, sqrt, rounded to f32, clamp 1e-12f
// ---------------------------------------------------------------------------
__global__ __launch_bounds__(256)
void cc_rownorm(const float* __restrict__ x, float* __restrict__ rn) {
  int row = blockIdx.x, tid = threadIdx.x;
  __shared__ double red[256];
  double s = 0.0;
  const float* xr = x + (size_t)row * DIM;
  for (int k = tid; k < DIM; k += 256) {
    double v = xr[k];
    s = fma(v, v, s);
  }
  red[tid] = s;
  __syncthreads();
  for (int off = 128; off > 0; off >>= 1) {
    if (tid < off) red[tid] += red[tid + off];
    __syncthreads();
  }
  if (tid == 0) rn[row] = fmaxf((float)sqrt(red[0]), 1e-12f);
}

// ---------------------------------------------------------------------------
// score[b,s,t]: identical numerics to round-5 (f32 store points). NEW:
// epilogue also emits per-(row, 64-col-tile) packed max keys
//   key = (ordered_u32(v) << 32) | (511 - col)
// so greedy needs no initial full scan. max-key compare == (v, then min col).
// ---------------------------------------------------------------------------
__global__ __launch_bounds__(256)
void cc_gemm_score(const float* __restrict__ X, const float* __restrict__ rn,
                   const float* __restrict__ w, float* __restrict__ score,
                   unsigned long long* __restrict__ tkeyG) {
  const int b = blockIdx.z;
  __shared__ double As[BK][66];
  __shared__ double Bs[BK][66];
  int tid = threadIdx.x;
  int tx = tid % 16, ty = tid / 16;
  int s0 = blockIdx.y * 64, t0 = blockIdx.x * 64;
  const float* Xb = X + (size_t)b * SEQ * DIM;
  const float* rnb = rn + b * SEQ;
  double acc[4][4] = {};
  for (int k0 = 0; k0 < DIM; k0 += BK) {
#pragma unroll
    for (int u = 0; u < 8; ++u) {
      int l = tid + u * 256;
      int r = l >> 5, k = l & 31;
      As[k][r] = (double)(Xb[(size_t)(s0 + r) * DIM + k0 + k] / rnb[s0 + r]);
      Bs[k][r] = (double)(Xb[(size_t)(t0 + r) * DIM + k0 + k] / rnb[t0 + r]);
    }
    __syncthreads();
#pragma unroll
    for (int k = 0; k < BK; ++k) {
      double a0 = As[k][ty * 4 + 0], a1 = As[k][ty * 4 + 1];
      double a2 = As[k][ty * 4 + 2], a3 = As[k][ty * 4 + 3];
      double b0 = Bs[k][tx * 4 + 0], b1 = Bs[k][tx * 4 + 1];
      double b2 = Bs[k][tx * 4 + 2], b3 = Bs[k][tx * 4 + 3];
      acc[0][0] = fma(a0, b0, acc[0][0]); acc[0][1] = fma(a0, b1, acc[0][1]);
      acc[0][2] = fma(a0, b2, acc[0][2]); acc[0][3] = fma(a0, b3, acc[0][3]);
      acc[1][0] = fma(a1, b0, acc[1][0]); acc[1][1] = fma(a1, b1, acc[1][1]);
      acc[1][2] = fma(a1, b2, acc[1][2]); acc[1][3] = fma(a1, b3, acc[1][3]);
      acc[2][0] = fma(a2, b0, acc[2][0]); acc[2][1] = fma(a2, b1, acc[2][1]);
      acc[2][2] = fma(a2, b2, acc[2][2]); acc[2][3] = fma(a2, b3, acc[2][3]);
      acc[3][0] = fma(a3, b0, acc[3][0]); acc[3][1] = fma(a3, b1, acc[3][1]);
      acc[3][2] = fma(a3, b2, acc[3][2]); acc[3][3] = fma(a3, b3, acc[3][3]);
    }
    __syncthreads();
  }
  unsigned long long key[4] = {0ULL, 0ULL, 0ULL, 0ULL};
#pragma unroll
  for (int i = 0; i < 4; ++i)
#pragma unroll
    for (int j = 0; j < 4; ++j) {
      int s = s0 + ty * 4 + i, t = t0 + tx * 4 + j;
      float v;
      if (s == t) v = -1.0f;
      else {
        float sim = (float)acc[i][j];                       // f32 store point
        float wp = w[b * SEQ + s] * w[b * SEQ + t];         // f32 multiply
        v = sim / wp;                                       // f32 divide
      }
      score[((size_t)b * SEQ + s) * SEQ + t] = v;
      unsigned u = __float_as_uint(v);
      unsigned ou = (u & 0x80000000u) ? ~u : (u | 0x80000000u);
      unsigned long long k = ((unsigned long long)ou << 32)
                           | (unsigned)((SEQ - 1) - t);
      if (k > key[i]) key[i] = k;
    }
#pragma unroll
  for (int i = 0; i < 4; ++i) {
#pragma unroll
    for (int off = 1; off < 16; off <<= 1) {
      unsigned long long ok = __shfl_xor(key[i], off, 64);
      if (ok > key[i]) key[i] = ok;
    }
    if (tx == 0)
      tkeyG[((size_t)b * SEQ + s0 + ty * 4 + i) * 8 + blockIdx.x] = key[i];
  }
}

// ---------------------------------------------------------------------------
// Greedy pair selection: ONE WAVE per batch, driven by per-tile max keys.
// LDS: 8 keys/row (32KB) + rarg broadcast + 512-bit avail mask. A rescan
// only re-reads stale 64-col stripes. Tie-breaks identical to flat argmax.
// ---------------------------------------------------------------------------
__global__ __launch_bounds__(64)
void cc_greedy(const float* __restrict__ score,
               const unsigned long long* __restrict__ tkeyG,
               int* __restrict__ pi, int* __restrict__ pj,
               unsigned char* __restrict__ availg) {
  const int b = blockIdx.x;
  const float* S = score + (size_t)b * SEQ * SEQ;
  const int lane = threadIdx.x;
  __shared__ unsigned long long tkeyL[SEQ * 8];
  __shared__ int rargL[SEQ];
  __shared__ unsigned abits[SEQ / 32];
  unsigned rhi8[8];
  int rarg8[8];
  unsigned am = 0xFFu;

  if (lane < SEQ / 32) abits[lane] = 0xFFFFFFFFu;
#pragma unroll
  for (int q = 0; q < 8; ++q) {
    int r = lane * 8 + q;
    const unsigned long long* tk = tkeyG + ((size_t)b * SEQ + r) * 8;
    unsigned long long best = 0ULL;
#pragma unroll
    for (int tt = 0; tt < 8; ++tt) {
      unsigned long long k = tk[tt];
      tkeyL[r * 8 + tt] = k;
      if (k > best) best = k;
    }
    rhi8[q] = (unsigned)(best >> 32);
    rarg8[q] = (SEQ - 1) - (int)(best & 0x3FFu);
    rargL[r] = rarg8[q];
  }
  __syncthreads();

  for (int t = 0; t < NPAIRS; ++t) {
    // wave argmax over rows: key = (rowmax_ordered, 511-row) -> min row on tie
    unsigned long long key = 0ULL;
#pragma unroll
    for (int q = 0; q < 8; ++q) {
      if (am & (1u << q)) {
        unsigned long long k = ((unsigned long long)rhi8[q] << 32)
                             | (unsigned)((SEQ - 1) - (lane * 8 + q));
        if (k > key) key = k;
      }
    }
#pragma unroll
    for (int off = 1; off < 64; off <<= 1) {
      unsigned long long ok = __shfl_xor(key, off, 64);
      if (ok > key) key = ok;
    }
    const int i = (SEQ - 1) - (int)(key & 0x3FFu);
    const int j = rargL[i];
    if (lane == 0) {
      pi[b * NPAIRS + t] = i;
      pj[b * NPAIRS + t] = j;
      abits[i >> 5] &= ~(1u << (i & 31));
      abits[j >> 5] &= ~(1u << (j & 31));
    }
    if ((i >> 3) == lane) am &= ~(1u << (i & 7));
    if ((j >> 3) == lane) am &= ~(1u << (j & 7));
    __syncthreads();
    // rows whose cached argmax col just died: refresh stale tiles only
#pragma unroll
    for (int q = 0; q < 8; ++q) {
      if ((am & (1u << q)) && (rarg8[q] == i || rarg8[q] == j)) {
        int r = lane * 8 + q;
        unsigned long long best = 0ULL;
#pragma unroll
        for (int tt = 0; tt < 8; ++tt) {
          unsigned long long k = tkeyL[r * 8 + tt];
          if (k != 0ULL) {
            int c = (SEQ - 1) - (int)(k & 0x3FFu);
            if (!((abits[c >> 5] >> (c & 31)) & 1u)) {
              // stale stripe: rescan 64 cols with avail-nibble skipping
              const float4* row4 = (const float4*)(S + (size_t)r * SEQ + tt * 64);
              float bv = -INFINITY; int bc = -1;
              for (int c4 = 0; c4 < 16; ++c4) {
                unsigned nib = (abits[tt * 2 + (c4 >> 3)] >> ((c4 & 7) * 4)) & 0xFu;
                if (!nib) continue;
                float4 v = row4[c4];
                int cc = c4 * 4;
                if ((nib & 1u) && v.x > bv) { bv = v.x; bc = cc; }
                if ((nib & 2u) && v.y > bv) { bv = v.y; bc = cc + 1; }
                if ((nib & 4u) && v.z > bv) { bv = v.z; bc = cc + 2; }
                if ((nib & 8u) && v.w > bv) { bv = v.w; bc = cc + 3; }
              }
              if (bc >= 0) {
                unsigned u = __float_as_uint(bv);
                unsigned ou = (u & 0x80000000u) ? ~u : (u | 0x80000000u);
                k = ((unsigned long long)ou << 32)
                  | (unsigned)((SEQ - 1) - (tt * 64 + bc));
              } else {
                k = 0ULL;
              }
              tkeyL[r * 8 + tt] = k;
            }
          }
          if (k > best) best = k;
        }
        rhi8[q] = (unsigned)(best >> 32);
        rarg8[q] = (SEQ - 1) - (int)(best & 0x3FFu);
        rargL[r] = rarg8[q];
      }
    }
    __syncthreads();
  }
#pragma unroll
  for (int q = 0; q < 8; ++q) {
    int r = lane * 8 + q;
    availg[b * SEQ + r] = (unsigned char)((abits[r >> 5] >> (r & 31)) & 1u);
  }
}

// ---------------------------------------------------------------------------
// unmerged index list via prefix sum (ascending order)
// ---------------------------------------------------------------------------
__global__ __launch_bounds__(512)
void cc_unmerged(const unsigned char* __restrict__ availg, int* __restrict__ un) {
  int b = blockIdx.x, tid = threadIdx.x;
  __shared__ int ps[SEQ];
  int flag = availg[b * SEQ + tid];
  ps[tid] = flag;
  __syncthreads();
  for (int off = 1; off < SEQ; off <<= 1) {
    int v = (tid >= off) ? ps[tid - off] : 0;
    __syncthreads();
    ps[tid] += v;
    __syncthreads();
  }
  int pos = ps[tid] - flag;
  if (flag && pos < NUN) un[b * NUN + pos] = tid;
}

// ---------------------------------------------------------------------------
// copy unmerged tokens to out rows [128, 384)
// ---------------------------------------------------------------------------
__global__ __launch_bounds__(256)
void cc_unmerged_copy(const float* __restrict__ x, const int* __restrict__ un,
                      float* __restrict__ out) {
  int idx = blockIdx.x;
  int b = idx / NUN, u_ = idx % NUN;
  int s = un[idx];
  const float4* src = (const float4*)(x + ((size_t)b * SEQ + s) * DIM);
  float4* dst = (float4*)(out + ((size_t)b * TLEN + NPAIRS + u_) * DIM);
  for (int u = threadIdx.x; u < DIM / 4; u += 256) dst[u] = src[u];
}

// ---------------------------------------------------------------------------
// m1 = gelu(pair @ mrg_w1 + b1); pair gathered from x via pi/pj on the fly.
// 128x128 tile, 8x8 per thread, f32.
// ---------------------------------------------------------------------------
__global__ __launch_bounds__(256)
void cc_gemm_m1f(const float* __restrict__ x, const int* __restrict__ pi,
                 const int* __restrict__ pj, const float* __restrict__ B,
                 const float* __restrict__ bias, float* __restrict__ C) {
  const int N = DIM, K = 2 * DIM;
  __shared__ float As[16][132];
  __shared__ float Bs[16][132];
  int tid = threadIdx.x;
  int tx = tid % 16, ty = tid / 16;
  int m0 = blockIdx.y * 128, n0 = blockIdx.x * 128;
  float acc[8][8] = {};
  for (int k0 = 0; k0 < K; k0 += 16) {
    const int* tokArr = (k0 < DIM) ? pi : pj;
    const int kc0 = (k0 < DIM) ? k0 : k0 - DIM;
#pragma unroll
    for (int u = 0; u < 8; ++u) {
      int l = tid + u * 256;
      int r = l >> 4, k = l & 15;
      int mg = m0 + r;
      int bb = mg >> 7;
      int tok = tokArr[mg];
      As[k][r] = x[((size_t)bb * SEQ + tok) * DIM + kc0 + k];
      int kb = l >> 7, n = l & 127;
      Bs[kb][n] = B[(size_t)(k0 + kb) * N + n0 + n];
    }
    __syncthreads();
#pragma unroll
    for (int k = 0; k < 16; ++k) {
      float a[8], bb_[8];
      *(float4*)&a[0] = *(const float4*)&As[k][ty * 8];
      *(float4*)&a[4] = *(const float4*)&As[k][ty * 8 + 4];
      *(float4*)&bb_[0] = *(const float4*)&Bs[k][tx * 8];
      *(float4*)&bb_[4] = *(const float4*)&Bs[k][tx * 8 + 4];
#pragma unroll
      for (int i = 0; i < 8; ++i)
#pragma unroll
        for (int j = 0; j < 8; ++j)
          acc[i][j] = fmaf(a[i], bb_[j], acc[i][j]);
    }
    __syncthreads();
  }
#pragma unroll
  for (int i = 0; i < 8; ++i)
#pragma unroll
    for (int j = 0; j < 8; ++j) {
      int m = m0 + ty * 8 + i, n = n0 + tx * 8 + j;
      float v = acc[i][j] + bias[n];
      float g = 0.5f * v * (1.0f + erff(v * 0.70710678f));
      C[(size_t)m * N + n] = g;
    }
}

// ---------------------------------------------------------------------------
// merged = m1 @ mrg_w2 + b2, scattered into out rows [0,128). 128x128 tile.
// ---------------------------------------------------------------------------
__global__ __launch_bounds__(256)
void cc_gemm_m2c(const float* __restrict__ A, const float* __restrict__ B,
                 const float* __restrict__ bias, float* __restrict__ out) {
  const int N = DIM, K = DIM;
  __shared__ float As[16][132];
  __shared__ float Bs[16][132];
  int tid = threadIdx.x;
  int tx = tid % 16, ty = tid / 16;
  int m0 = blockIdx.y * 128, n0 = blockIdx.x * 128;
  float acc[8][8] = {};
  for (int k0 = 0; k0 < K; k0 += 16) {
#pragma unroll
    for (int u = 0; u < 8; ++u) {
      int l = tid + u * 256;
      int r = l >> 4, k = l & 15;
      As[k][r] = A[(size_t)(m0 + r) * K + k0 + k];
      int kb = l >> 7, n = l & 127;
      Bs[kb][n] = B[(size_t)(k0 + kb) * N + n0 + n];
    }
    __syncthreads();
#pragma unroll
    for (int k = 0; k < 16; ++k) {
      float a[8], bb_[8];
      *(float4*)&a[0] = *(const float4*)&As[k][ty * 8];
      *(float4*)&a[4] = *(const float4*)&As[k][ty * 8 + 4];
      *(float4*)&bb_[0] = *(const float4*)&Bs[k][tx * 8];
      *(float4*)&bb_[4] = *(const float4*)&Bs[k][tx * 8 + 4];
#pragma unroll
      for (int i = 0; i < 8; ++i)
#pragma unroll
        for (int j = 0; j < 8; ++j)
          acc[i][j] = fmaf(a[i], bb_[j], acc[i][j]);
    }
    __syncthreads();
  }
#pragma unroll
  for (int i = 0; i < 8; ++i)
#pragma unroll
    for (int j = 0; j < 8; ++j) {
      int m = m0 + ty * 8 + i, n = n0 + tx * 8 + j;
      int bb = m >> 7, p = m & 127;
      float v = acc[i][j] + bias[n];
      out[((size_t)bb * TLEN + p) * N + n] = v;
    }
}

extern "C" void kernel_launch(void* const* d_in, const int* in_sizes, int n_in,
                              void* d_out, int out_size, void* d_ws, size_t ws_size,
                              hipStream_t stream) {
  const float* x      = (const float*)d_in[0];
  const float* imp_w1 = (const float*)d_in[1];
  const float* imp_b1 = (const float*)d_in[2];
  const float* imp_w2 = (const float*)d_in[3];
  const float* imp_b2 = (const float*)d_in[4];
  const float* mrg_w1 = (const float*)d_in[5];
  const float* mrg_b1 = (const float*)d_in[6];
  const float* mrg_w2 = (const float*)d_in[7];
  const float* mrg_b2 = (const float*)d_in[8];
  float* out = (float*)d_out;

  // score (16 MB f32) lives in d_out — fully consumed before output writes.
  float* score = (float*)d_out;

  // workspace (~49 MB)
  char* ws = (char*)d_ws;
  float* hbuf  = (float*)ws;                               // 32 MB
  float* m1buf = (float*)(ws + ((size_t)32 << 20));        // 16 MB
  char* sm = ws + ((size_t)48 << 20);
  unsigned long long* tkey = (unsigned long long*)sm;
  sm += (size_t)BATCH * SEQ * 8 * 8;                       // 512 KB
  float* imp = (float*)sm;              sm += (size_t)BATCH * SEQ * 4;
  float* wv  = (float*)sm;              sm += (size_t)BATCH * SEQ * 4;
  float* rn  = (float*)sm;              sm += (size_t)BATCH * SEQ * 4;
  int* pi    = (int*)sm;                sm += (size_t)BATCH * NPAIRS * 4;
  int* pj    = (int*)sm;                sm += (size_t)BATCH * NPAIRS * 4;
  unsigned char* avail = (unsigned char*)sm; sm += (size_t)BATCH * SEQ;
  int* un    = (int*)sm;                sm += (size_t)BATCH * NUN * 4;

  cc_rownorm<<<BATCH * SEQ, 256, 0, stream>>>(x, rn);
  cc_gemm_h<<<dim3(HID / 64, BATCH * SEQ / 64), 256, 0, stream>>>(x, imp_w1, imp_b1, hbuf);
  cc_imp2<<<BATCH * SEQ, 256, 0, stream>>>(hbuf, imp_w2, imp_b2, imp);
  cc_minmax<<<BATCH, 512, 0, stream>>>(imp, wv);
  cc_gemm_score<<<dim3(SEQ / 64, SEQ / 64, BATCH), 256, 0, stream>>>(x, rn, wv, score, tkey);
  cc_greedy<<<BATCH, 64, 0, stream>>>(score, tkey, pi, pj, avail);
  cc_unmerged<<<BATCH, SEQ, 0, stream>>>(avail, un);
  // score (in d_out) dead from here; start writing outputs.
  cc_unmerged_copy<<<BATCH * NUN, 256, 0, stream>>>(x, un, out);
  cc_gemm_m1f<<<dim3(DIM / 128, BATCH * NPAIRS / 128), 256, 0, stream>>>(
      x, pi, pj, mrg_w1, mrg_b1, m1buf);
  cc_gemm_m2c<<<dim3(DIM / 128, BATCH * NPAIRS / 128), 256, 0, stream>>>(
      m1buf, mrg_w2, mrg_b2, out);
}

// Round 7
// 3946.677 us; speedup vs baseline: 3.4605x; 3.4605x over previous
//
#include <hip/hip_runtime.h>
#include <math.h>

#define BATCH 16
#define SEQ 512
#define DIM 2048
#define HID 1024
#define NPAIRS 128
#define TLEN 384
#define NUN 256
#define BK 32

// ---------------------------------------------------------------------------
// GEMM 1: h = gelu(x @ imp_w1 + b1). fp64 accumulate (ascending k — bit-exact
// vs round-4/5/6), f64 tiles in LDS. 64x64 tile, BK=32.  (selection path!)
// ---------------------------------------------------------------------------
__global__ __launch_bounds__(256)
void cc_gemm_h(const float* __restrict__ A, const float* __restrict__ Bw,
               const float* __restrict__ bias, float* __restrict__ C) {
  const int N = HID, K = DIM;
  __shared__ double As[BK][66];
  __shared__ double Bs[BK][66];
  int tid = threadIdx.x;
  int tx = tid % 16, ty = tid / 16;
  int m0 = blockIdx.y * 64, n0 = blockIdx.x * 64;
  double acc[4][4] = {};
  for (int k0 = 0; k0 < K; k0 += BK) {
#pragma unroll
    for (int u = 0; u < 8; ++u) {
      int l = tid + u * 256;
      int r = l >> 5, k = l & 31;
      As[k][r] = (double)A[(size_t)(m0 + r) * K + k0 + k];
      int kb = l >> 6, n = l & 63;
      Bs[kb][n] = (double)Bw[(size_t)(k0 + kb) * N + n0 + n];
    }
    __syncthreads();
#pragma unroll
    for (int k = 0; k < BK; ++k) {
      double a0 = As[k][ty * 4 + 0], a1 = As[k][ty * 4 + 1];
      double a2 = As[k][ty * 4 + 2], a3 = As[k][ty * 4 + 3];
      double b0 = Bs[k][tx * 4 + 0], b1 = Bs[k][tx * 4 + 1];
      double b2 = Bs[k][tx * 4 + 2], b3 = Bs[k][tx * 4 + 3];
      acc[0][0] = fma(a0, b0, acc[0][0]); acc[0][1] = fma(a0, b1, acc[0][1]);
      acc[0][2] = fma(a0, b2, acc[0][2]); acc[0][3] = fma(a0, b3, acc[0][3]);
      acc[1][0] = fma(a1, b0, acc[1][0]); acc[1][1] = fma(a1, b1, acc[1][1]);
      acc[1][2] = fma(a1, b2, acc[1][2]); acc[1][3] = fma(a1, b3, acc[1][3]);
      acc[2][0] = fma(a2, b0, acc[2][0]); acc[2][1] = fma(a2, b1, acc[2][1]);
      acc[2][2] = fma(a2, b2, acc[2][2]); acc[2][3] = fma(a2, b3, acc[2][3]);
      acc[3][0] = fma(a3, b0, acc[3][0]); acc[3][1] = fma(a3, b1, acc[3][1]);
      acc[3][2] = fma(a3, b2, acc[3][2]); acc[3][3] = fma(a3, b3, acc[3][3]);
    }
    __syncthreads();
  }
#pragma unroll
  for (int i = 0; i < 4; ++i)
#pragma unroll
    for (int j = 0; j < 4; ++j) {
      int m = m0 + ty * 4 + i, n = n0 + tx * 4 + j;
      float pre = (float)(acc[i][j] + (double)bias[n]);     // f32 store point
      double v = (double)pre;
      double g = 0.5 * v * (1.0 + erf(v * 0.70710678118654752440));
      C[(size_t)m * N + n] = (float)g;                      // f32 store point
    }
}

// ---------------------------------------------------------------------------
// imp = sigmoid(h @ imp_w2 + b2); logit rounded to f32, imp stored f32
// ---------------------------------------------------------------------------
__global__ __launch_bounds__(256)
void cc_imp2(const float* __restrict__ h, const float* __restrict__ w2,
             const float* __restrict__ b2, float* __restrict__ imp) {
  int row = blockIdx.x, tid = threadIdx.x;
  __shared__ double red[256];
  double s = 0.0;
  const float* hr = h + (size_t)row * HID;
  for (int k = tid; k < HID; k += 256) s = fma((double)hr[k], (double)w2[k], s);
  red[tid] = s;
  __syncthreads();
  for (int off = 128; off > 0; off >>= 1) {
    if (tid < off) red[tid] += red[tid + off];
    __syncthreads();
  }
  if (tid == 0) {
    float logit = (float)(red[0] + (double)b2[0]);          // f32 store point
    double sg = 1.0 / (1.0 + exp(-(double)logit));
    imp[row] = (float)sg;                                   // f32 store point
  }
}

// ---------------------------------------------------------------------------
// per-batch min-max normalize in f32, then w = max(norm, 0.1f)
// ---------------------------------------------------------------------------
__global__ __launch_bounds__(512)
void cc_minmax(const float* __restrict__ imp, float* __restrict__ w) {
  int b = blockIdx.x, tid = threadIdx.x;
  __shared__ float mn[512], mx[512];
  float v = imp[b * SEQ + tid];
  mn[tid] = v; mx[tid] = v;
  __syncthreads();
  for (int off = 256; off > 0; off >>= 1) {
    if (tid < off) {
      mn[tid] = fminf(mn[tid], mn[tid + off]);
      mx[tid] = fmaxf(mx[tid], mx[tid + off]);
    }
    __syncthreads();
  }
  float lo = mn[0], hi = mx[0];
  float nv = (hi > lo) ? (v - lo) / (hi - lo) : v;
  w[b * SEQ + tid] = fmaxf(nv, 0.1f);
}

// ---------------------------------------------------------------------------
// row L2 norms of x: exact f64 sumsq, sqrt, rounded to f32, clamp 1e-12f
// ---------------------------------------------------------------------------
__global__ __launch_bounds__(256)
void cc_rownorm(const float* __restrict__ x, float* __restrict__ rn) {
  int row = blockIdx.x, tid = threadIdx.x;
  __shared__ double red[256];
  double s = 0.0;
  const float* xr = x + (size_t)row * DIM;
  for (int k = tid; k < DIM; k += 256) {
    double v = xr[k];
    s = fma(v, v, s);
  }
  red[tid] = s;
  __syncthreads();
  for (int off = 128; off > 0; off >>= 1) {
    if (tid < off) red[tid] += red[tid + off];
    __syncthreads();
  }
  if (tid == 0) rn[row] = fmaxf((float)sqrt(red[0]), 1e-12f);
}

// ---------------------------------------------------------------------------
// score[b,s,t]: xn = x/rn (f32 div at staging), f64-exact dot -> f32 sim,
// wprod f32 mul, score = sim/wprod f32 div; diag -1.0f.  BK=32, f64 LDS.
// (identical numerics to rounds 4-6; tkey epilogue removed)
// ---------------------------------------------------------------------------
__global__ __launch_bounds__(256)
void cc_gemm_score(const float* __restrict__ X, const float* __restrict__ rn,
                   const float* __restrict__ w, float* __restrict__ score) {
  const int b = blockIdx.z;
  __shared__ double As[BK][66];
  __shared__ double Bs[BK][66];
  int tid = threadIdx.x;
  int tx = tid % 16, ty = tid / 16;
  int s0 = blockIdx.y * 64, t0 = blockIdx.x * 64;
  const float* Xb = X + (size_t)b * SEQ * DIM;
  const float* rnb = rn + b * SEQ;
  double acc[4][4] = {};
  for (int k0 = 0; k0 < DIM; k0 += BK) {
#pragma unroll
    for (int u = 0; u < 8; ++u) {
      int l = tid + u * 256;
      int r = l >> 5, k = l & 31;
      As[k][r] = (double)(Xb[(size_t)(s0 + r) * DIM + k0 + k] / rnb[s0 + r]);
      Bs[k][r] = (double)(Xb[(size_t)(t0 + r) * DIM + k0 + k] / rnb[t0 + r]);
    }
    __syncthreads();
#pragma unroll
    for (int k = 0; k < BK; ++k) {
      double a0 = As[k][ty * 4 + 0], a1 = As[k][ty * 4 + 1];
      double a2 = As[k][ty * 4 + 2], a3 = As[k][ty * 4 + 3];
      double b0 = Bs[k][tx * 4 + 0], b1 = Bs[k][tx * 4 + 1];
      double b2 = Bs[k][tx * 4 + 2], b3 = Bs[k][tx * 4 + 3];
      acc[0][0] = fma(a0, b0, acc[0][0]); acc[0][1] = fma(a0, b1, acc[0][1]);
      acc[0][2] = fma(a0, b2, acc[0][2]); acc[0][3] = fma(a0, b3, acc[0][3]);
      acc[1][0] = fma(a1, b0, acc[1][0]); acc[1][1] = fma(a1, b1, acc[1][1]);
      acc[1][2] = fma(a1, b2, acc[1][2]); acc[1][3] = fma(a1, b3, acc[1][3]);
      acc[2][0] = fma(a2, b0, acc[2][0]); acc[2][1] = fma(a2, b1, acc[2][1]);
      acc[2][2] = fma(a2, b2, acc[2][2]); acc[2][3] = fma(a2, b3, acc[2][3]);
      acc[3][0] = fma(a3, b0, acc[3][0]); acc[3][1] = fma(a3, b1, acc[3][1]);
      acc[3][2] = fma(a3, b2, acc[3][2]); acc[3][3] = fma(a3, b3, acc[3][3]);
    }
    __syncthreads();
  }
#pragma unroll
  for (int i = 0; i < 4; ++i)
#pragma unroll
    for (int j = 0; j < 4; ++j) {
      int s = s0 + ty * 4 + i, t = t0 + tx * 4 + j;
      float v;
      if (s == t) v = -1.0f;
      else {
        float sim = (float)acc[i][j];                       // f32 store point
        float wp = w[b * SEQ + s] * w[b * SEQ + t];         // f32 multiply
        v = sim / wp;                                       // f32 divide
      }
      score[((size_t)b * SEQ + s) * SEQ + t] = v;
    }
}

// ---------------------------------------------------------------------------
// Greedy pair selection: ONE WAVE per batch.
//  - init: each lane scans its own 8 rows independently (no shuffles)
//  - pick: 8 reg key-compares + 6-stage u64 shfl max + LDS broadcast
//  - refresh: wave-parallel full-row rescan, ballot-serialized over the
//    (few) rows whose cached argmax column just died
// Packed keys (ordered_f32<<32)|(511-idx) reproduce flat-argmax tie-breaks
// exactly: max value, then min row, then min col.
// ---------------------------------------------------------------------------
__global__ __launch_bounds__(64)
void cc_greedy(const float* __restrict__ score, int* __restrict__ pi,
               int* __restrict__ pj, unsigned char* __restrict__ availg) {
  const int b = blockIdx.x;
  const float* S = score + (size_t)b * SEQ * SEQ;
  const int lane = threadIdx.x;
  __shared__ uint2 availv[SEQ / 8];
  unsigned char* avail = (unsigned char*)availv;
  __shared__ int rargL[SEQ];
  __shared__ int spi[NPAIRS], spj[NPAIRS];
  unsigned rhi8[8];   // ordered-u32 row max
  int rarg8[8];       // its column
  unsigned am = 0xFFu;

  availv[lane] = make_uint2(0x01010101u, 0x01010101u);

  // ---- init: 8 independent row scans per lane (ILP across rows) ----
  {
    float bv[8]; int bc[8];
#pragma unroll
    for (int q = 0; q < 8; ++q) { bv[q] = -INFINITY; bc[q] = 0; }
    for (int c4 = 0; c4 < SEQ / 4; ++c4) {
#pragma unroll
      for (int q = 0; q < 8; ++q) {
        int r = lane * 8 + q;
        float4 v = ((const float4*)(S + (size_t)r * SEQ))[c4];
        int cc = c4 * 4;
        if (v.x > bv[q]) { bv[q] = v.x; bc[q] = cc; }
        if (v.y > bv[q]) { bv[q] = v.y; bc[q] = cc + 1; }
        if (v.z > bv[q]) { bv[q] = v.z; bc[q] = cc + 2; }
        if (v.w > bv[q]) { bv[q] = v.w; bc[q] = cc + 3; }
      }
    }
#pragma unroll
    for (int q = 0; q < 8; ++q) {
      unsigned u = __float_as_uint(bv[q]);
      rhi8[q] = (u & 0x80000000u) ? ~u : (u | 0x80000000u);
      rarg8[q] = bc[q];
      rargL[lane * 8 + q] = bc[q];
    }
  }
  __syncthreads();

  for (int t = 0; t < NPAIRS; ++t) {
    // ---- pick: argmax over available rows' cached maxima ----
    unsigned long long key = 0ULL;
#pragma unroll
    for (int q = 0; q < 8; ++q) {
      if (am & (1u << q)) {
        unsigned long long k = ((unsigned long long)rhi8[q] << 32)
                             | (unsigned)((SEQ - 1) - (lane * 8 + q));
        if (k > key) key = k;
      }
    }
#pragma unroll
    for (int off = 1; off < 64; off <<= 1) {
      unsigned long long ok = __shfl_xor(key, off, 64);
      if (ok > key) key = ok;
    }
    const int i = (SEQ - 1) - (int)(key & 0xFFFFFFFFull);
    const int j = rargL[i];
    if (lane == 0) {
      spi[t] = i; spj[t] = j;
      avail[i] = 0; avail[j] = 0;
    }
    if ((i >> 3) == lane) am &= ~(1u << (i & 7));
    if ((j >> 3) == lane) am &= ~(1u << (j & 7));
    __syncthreads();

    // ---- refresh rows whose cached argmax column just died ----
    unsigned needmask = 0u;
#pragma unroll
    for (int q = 0; q < 8; ++q)
      if ((am & (1u << q)) && (rarg8[q] == i || rarg8[q] == j))
        needmask |= (1u << q);
    for (int q = 0; q < 8; ++q) {
      unsigned long long m = __ballot((needmask >> q) & 1u);
      while (m) {
        int src = __ffsll(m) - 1;
        m &= m - 1;
        int r = src * 8 + q;
        // wave-parallel rescan of row r: lane covers cols lane*8..lane*8+7
        const float4* row4 = (const float4*)(S + (size_t)r * SEQ) + lane * 2;
        float4 v0 = row4[0], v1 = row4[1];
        uint2 av = availv[lane];
        float nv = -INFINITY; int nc = -1;
        if ((av.x & 0x000000FFu) && v0.x > nv) { nv = v0.x; nc = 0; }
        if ((av.x & 0x0000FF00u) && v0.y > nv) { nv = v0.y; nc = 1; }
        if ((av.x & 0x00FF0000u) && v0.z > nv) { nv = v0.z; nc = 2; }
        if ((av.x & 0xFF000000u) && v0.w > nv) { nv = v0.w; nc = 3; }
        if ((av.y & 0x000000FFu) && v1.x > nv) { nv = v1.x; nc = 4; }
        if ((av.y & 0x0000FF00u) && v1.y > nv) { nv = v1.y; nc = 5; }
        if ((av.y & 0x00FF0000u) && v1.z > nv) { nv = v1.z; nc = 6; }
        if ((av.y & 0xFF000000u) && v1.w > nv) { nv = v1.w; nc = 7; }
        unsigned long long rk = 0ULL;
        if (nc >= 0) {
          unsigned u = __float_as_uint(nv);
          unsigned ou = (u & 0x80000000u) ? ~u : (u | 0x80000000u);
          rk = ((unsigned long long)ou << 32)
             | (unsigned)((SEQ - 1) - (lane * 8 + nc));
        }
#pragma unroll
        for (int off = 1; off < 64; off <<= 1) {
          unsigned long long ok = __shfl_xor(rk, off, 64);
          if (ok > rk) rk = ok;
        }
        if (lane == src) {
          rhi8[q] = (unsigned)(rk >> 32);
          rarg8[q] = (SEQ - 1) - (int)(rk & 0xFFFFFFFFull);
          rargL[r] = rarg8[q];
        }
      }
    }
    __syncthreads();
  }

  for (int t2 = lane; t2 < NPAIRS; t2 += 64) {
    pi[b * NPAIRS + t2] = spi[t2];
    pj[b * NPAIRS + t2] = spj[t2];
  }
#pragma unroll
  for (int q = 0; q < 8; ++q) {
    int r = lane * 8 + q;
    availg[b * SEQ + r] = avail[r];
  }
}

// ---------------------------------------------------------------------------
// unmerged index list via prefix sum (ascending order)
// ---------------------------------------------------------------------------
__global__ __launch_bounds__(512)
void cc_unmerged(const unsigned char* __restrict__ availg, int* __restrict__ un) {
  int b = blockIdx.x, tid = threadIdx.x;
  __shared__ int ps[SEQ];
  int flag = availg[b * SEQ + tid];
  ps[tid] = flag;
  __syncthreads();
  for (int off = 1; off < SEQ; off <<= 1) {
    int v = (tid >= off) ? ps[tid - off] : 0;
    __syncthreads();
    ps[tid] += v;
    __syncthreads();
  }
  int pos = ps[tid] - flag;
  if (flag && pos < NUN) un[b * NUN + pos] = tid;
}

// ---------------------------------------------------------------------------
// copy unmerged tokens to out rows [128, 384)
// ---------------------------------------------------------------------------
__global__ __launch_bounds__(256)
void cc_unmerged_copy(const float* __restrict__ x, const int* __restrict__ un,
                      float* __restrict__ out) {
  int idx = blockIdx.x;
  int b = idx / NUN, u_ = idx % NUN;
  int s = un[idx];
  const float4* src = (const float4*)(x + ((size_t)b * SEQ + s) * DIM);
  float4* dst = (float4*)(out + ((size_t)b * TLEN + NPAIRS + u_) * DIM);
  for (int u = threadIdx.x; u < DIM / 4; u += 256) dst[u] = src[u];
}

// ---------------------------------------------------------------------------
// m1 = gelu(pair @ mrg_w1 + b1); pair gathered from x via pi/pj on the fly.
// 128x128 tile, 8x8 per thread, f32.
// ---------------------------------------------------------------------------
__global__ __launch_bounds__(256)
void cc_gemm_m1f(const float* __restrict__ x, const int* __restrict__ pi,
                 const int* __restrict__ pj, const float* __restrict__ B,
                 const float* __restrict__ bias, float* __restrict__ C) {
  const int N = DIM, K = 2 * DIM;
  __shared__ float As[16][132];
  __shared__ float Bs[16][132];
  int tid = threadIdx.x;
  int tx = tid % 16, ty = tid / 16;
  int m0 = blockIdx.y * 128, n0 = blockIdx.x * 128;
  float acc[8][8] = {};
  for (int k0 = 0; k0 < K; k0 += 16) {
    const int* tokArr = (k0 < DIM) ? pi : pj;
    const int kc0 = (k0 < DIM) ? k0 : k0 - DIM;
#pragma unroll
    for (int u = 0; u < 8; ++u) {
      int l = tid + u * 256;
      int r = l >> 4, k = l & 15;
      int mg = m0 + r;
      int bb = mg >> 7;
      int tok = tokArr[mg];
      As[k][r] = x[((size_t)bb * SEQ + tok) * DIM + kc0 + k];
      int kb = l >> 7, n = l & 127;
      Bs[kb][n] = B[(size_t)(k0 + kb) * N + n0 + n];
    }
    __syncthreads();
#pragma unroll
    for (int k = 0; k < 16; ++k) {
      float a[8], bb_[8];
      *(float4*)&a[0] = *(const float4*)&As[k][ty * 8];
      *(float4*)&a[4] = *(const float4*)&As[k][ty * 8 + 4];
      *(float4*)&bb_[0] = *(const float4*)&Bs[k][tx * 8];
      *(float4*)&bb_[4] = *(const float4*)&Bs[k][tx * 8 + 4];
#pragma unroll
      for (int i = 0; i < 8; ++i)
#pragma unroll
        for (int j = 0; j < 8; ++j)
          acc[i][j] = fmaf(a[i], bb_[j], acc[i][j]);
    }
    __syncthreads();
  }
#pragma unroll
  for (int i = 0; i < 8; ++i)
#pragma unroll
    for (int j = 0; j < 8; ++j) {
      int m = m0 + ty * 8 + i, n = n0 + tx * 8 + j;
      float v = acc[i][j] + bias[n];
      float g = 0.5f * v * (1.0f + erff(v * 0.70710678f));
      C[(size_t)m * N + n] = g;
    }
}

// ---------------------------------------------------------------------------
// merged = m1 @ mrg_w2 + b2, scattered into out rows [0,128). 128x128 tile.
// ---------------------------------------------------------------------------
__global__ __launch_bounds__(256)
void cc_gemm_m2c(const float* __restrict__ A, const float* __restrict__ B,
                 const float* __restrict__ bias, float* __restrict__ out) {
  const int N = DIM, K = DIM;
  __shared__ float As[16][132];
  __shared__ float Bs[16][132];
  int tid = threadIdx.x;
  int tx = tid % 16, ty = tid / 16;
  int m0 = blockIdx.y * 128, n0 = blockIdx.x * 128;
  float acc[8][8] = {};
  for (int k0 = 0; k0 < K; k0 += 16) {
#pragma unroll
    for (int u = 0; u < 8; ++u) {
      int l = tid + u * 256;
      int r = l >> 4, k = l & 15;
      As[k][r] = A[(size_t)(m0 + r) * K + k0 + k];
      int kb = l >> 7, n = l & 127;
      Bs[kb][n] = B[(size_t)(k0 + kb) * N + n0 + n];
    }
    __syncthreads();
#pragma unroll
    for (int k = 0; k < 16; ++k) {
      float a[8], bb_[8];
      *(float4*)&a[0] = *(const float4*)&As[k][ty * 8];
      *(float4*)&a[4] = *(const float4*)&As[k][ty * 8 + 4];
      *(float4*)&bb_[0] = *(const float4*)&Bs[k][tx * 8];
      *(float4*)&bb_[4] = *(const float4*)&Bs[k][tx * 8 + 4];
#pragma unroll
      for (int i = 0; i < 8; ++i)
#pragma unroll
        for (int j = 0; j < 8; ++j)
          acc[i][j] = fmaf(a[i], bb_[j], acc[i][j]);
    }
    __syncthreads();
  }
#pragma unroll
  for (int i = 0; i < 8; ++i)
#pragma unroll
    for (int j = 0; j < 8; ++j) {
      int m = m0 + ty * 8 + i, n = n0 + tx * 8 + j;
      int bb = m >> 7, p = m & 127;
      float v = acc[i][j] + bias[n];
      out[((size_t)bb * TLEN + p) * N + n] = v;
    }
}

extern "C" void kernel_launch(void* const* d_in, const int* in_sizes, int n_in,
                              void* d_out, int out_size, void* d_ws, size_t ws_size,
                              hipStream_t stream) {
  const float* x      = (const float*)d_in[0];
  const float* imp_w1 = (const float*)d_in[1];
  const float* imp_b1 = (const float*)d_in[2];
  const float* imp_w2 = (const float*)d_in[3];
  const float* imp_b2 = (const float*)d_in[4];
  const float* mrg_w1 = (const float*)d_in[5];
  const float* mrg_b1 = (const float*)d_in[6];
  const float* mrg_w2 = (const float*)d_in[7];
  const float* mrg_b2 = (const float*)d_in[8];
  float* out = (float*)d_out;

  // score (16 MB f32) lives in d_out — fully consumed before output writes.
  float* score = (float*)d_out;

  // workspace (~48.2 MB)
  char* ws = (char*)d_ws;
  float* hbuf  = (float*)ws;                               // 32 MB
  float* m1buf = (float*)(ws + ((size_t)32 << 20));        // 16 MB
  char* sm = ws + ((size_t)48 << 20);
  float* imp = (float*)sm;              sm += (size_t)BATCH * SEQ * 4;
  float* wv  = (float*)sm;              sm += (size_t)BATCH * SEQ * 4;
  float* rn  = (float*)sm;              sm += (size_t)BATCH * SEQ * 4;
  int* pi    = (int*)sm;                sm += (size_t)BATCH * NPAIRS * 4;
  int* pj    = (int*)sm;                sm += (size_t)BATCH * NPAIRS * 4;
  unsigned char* avail = (unsigned char*)sm; sm += (size_t)BATCH * SEQ;
  int* un    = (int*)sm;                sm += (size_t)BATCH * NUN * 4;

  cc_rownorm<<<BATCH * SEQ, 256, 0, stream>>>(x, rn);
  cc_gemm_h<<<dim3(HID / 64, BATCH * SEQ / 64), 256, 0, stream>>>(x, imp_w1, imp_b1, hbuf);
  cc_imp2<<<BATCH * SEQ, 256, 0, stream>>>(hbuf, imp_w2, imp_b2, imp);
  cc_minmax<<<BATCH, 512, 0, stream>>>(imp, wv);
  cc_gemm_score<<<dim3(SEQ / 64, SEQ / 64, BATCH), 256, 0, stream>>>(x, rn, wv, score);
  cc_greedy<<<BATCH, 64, 0, stream>>>(score, pi, pj, avail);
  cc_unmerged<<<BATCH, SEQ, 0, stream>>>(avail, un);
  // score (in d_out) dead from here; start writing outputs.
  cc_unmerged_copy<<<BATCH * NUN, 256, 0, stream>>>(x, un, out);
  cc_gemm_m1f<<<dim3(DIM / 128, BATCH * NPAIRS / 128), 256, 0, stream>>>(
      x, pi, pj, mrg_w1, mrg_b1, m1buf);
  cc_gemm_m2c<<<dim3(DIM / 128, BATCH * NPAIRS / 128), 256, 0, stream>>>(
      m1buf, mrg_w2, mrg_b2, out);
}